// Round 8
// baseline (2308.512 us; speedup 1.0000x reference)
//
#include <hip/hip_runtime.h>
#include <hip/hip_bf16.h>

#define VOCAB  400000
#define EMB    300
#define HIDDEN 128
#define OUT    3
#define SEQ    4096
#define SPB    8     // sequences per block in the xproj kernel
#define CHUNK  64    // xp timesteps staged per LDS buffer
#define NCHUNK (SEQ / CHUNK)

typedef float f32x4 __attribute__((ext_vector_type(4)));

// bijective float4-slot swizzle: slot s lives at s + (s>>3)  (max 34 < 36)
#define SWZ(s) ((s) + ((s) >> 3))

// ---------------------------------------------------------------------------
// Kernel A: xproj[s][i] = b_ih[i] + dot(weights[X[s]], W_ih[i])  (unchanged)
// ---------------------------------------------------------------------------
__global__ __launch_bounds__(128) void xproj_kernel(
    const int* __restrict__ X, const float* __restrict__ weights,
    const float* __restrict__ W_ih, const float* __restrict__ b_ih,
    float* __restrict__ xproj)
{
    __shared__ float emb[SPB][EMB];
    __shared__ int xs[SPB];
    const int tid = threadIdx.x;
    const int s0 = blockIdx.x * SPB;

    if (tid < SPB) xs[tid] = X[s0 + tid];
    __syncthreads();

    {
        const float4* w4 = (const float4*)weights;
        float4* e4 = (float4*)&emb[0][0];
        for (int i = tid; i < SPB * (EMB / 4); i += 128) {
            int s = i / (EMB / 4);
            int r = i - s * (EMB / 4);
            e4[i] = w4[(size_t)xs[s] * (EMB / 4) + r];
        }
    }
    __syncthreads();

    const float4* wrow = (const float4*)(W_ih + tid * EMB);
    float acc[SPB];
    #pragma unroll
    for (int s = 0; s < SPB; ++s) acc[s] = 0.f;

    #pragma unroll 5
    for (int r = 0; r < EMB / 4; ++r) {
        float4 w = wrow[r];
        #pragma unroll
        for (int s = 0; s < SPB; ++s) {
            float4 e = *(const float4*)&emb[s][4 * r];   // uniform broadcast
            acc[s] += w.x * e.x;
            acc[s] += w.y * e.y;
            acc[s] += w.z * e.z;
            acc[s] += w.w * e.w;
        }
    }

    const float b = b_ih[tid];
    #pragma unroll
    for (int s = 0; s < SPB; ++s)
        xproj[(size_t)(s0 + s) * HIDDEN + tid] = acc[s] + b;
}

// ---------------------------------------------------------------------------
// Full-rate VALU cross-lane adds via DPP (no LDS round-trips).
// ---------------------------------------------------------------------------
template <int CTRL>
__device__ __forceinline__ float dpp_add(float x) {
    int t = __builtin_amdgcn_update_dpp(0, __float_as_int(x), CTRL, 0xF, 0xF, true);
    return x + __int_as_float(t);
}
// reduce across a 16-lane row; every lane ends with the full sum.
// row_ror:8 = 0x128, row_ror:4 = 0x124, quad_perm[2,3,0,1] = 0x4E,
// quad_perm[1,0,3,2] = 0xB1.
__device__ __forceinline__ float row16_reduce_add(float x) {
    x = dpp_add<0x128>(x);
    x = dpp_add<0x124>(x);
    x = dpp_add<0x4E>(x);
    x = dpp_add<0xB1>(x);
    return x;
}

// LDS-only barrier: lgkmcnt(0) + s_barrier, NO vmcnt drain -> outstanding
// global loads (xp chunk prefetch) stay in flight across steps.
__device__ __forceinline__ void step_barrier() {
    asm volatile("s_waitcnt lgkmcnt(0)" ::: "memory");
    __builtin_amdgcn_s_barrier();
}

// ---------------------------------------------------------------------------
// Kernel B: sequential Elman scan + fc + log_softmax.
// 1 block x 512 threads (8 waves, 2/SIMD).
// DS-THROUGHPUT-AWARE decomposition (round-7 lesson: DS pipe is per-CU,
// ~12 cy per ds_read_b128; old layout issued 64/step = 768 cy = the time):
//   * output-quad og = tid>>4 (0..31): 16 lanes per output-quad.
//   * lane li = tid&15 covers k = 8li..8li+7 -> reads just 2 ds_read_b128
//     of h per step (16 b128/step per CU = 192 cy, 4x less DS time).
//   * 16-way partial reduction entirely on VALU DPP (ror8/ror4/quads).
//   * h stored float4-slot-swizzled (s -> s+(s>>3)): strided reads are
//     <=2-way bank aliased (free, m136), and writes stay bijective.
//   * raw s_barrier + lgkmcnt(0) per step: no vmcnt(0) drain, so the
//     64-step-chunk xp prefetch (register relay -> LDS) truly overlaps.
// ---------------------------------------------------------------------------
__global__ __launch_bounds__(512, 2) void rnn_scan_kernel(
    const float* __restrict__ xproj, const float* __restrict__ W_hh,
    const float* __restrict__ b_hh, const float* __restrict__ W_fc,
    const float* __restrict__ b_fc, float* __restrict__ out)
{
    __shared__ f32x4 h_swz[2][36];               // swizzled h, double-buffered
    __shared__ float xp_lds[2][CHUNK * HIDDEN];  // 2 x 32 KB
    __shared__ float lg[OUT];

    const int tid   = threadIdx.x;
    const int li    = tid & 15;       // k-slice within output-quad group
    const int og    = tid >> 4;       // output-quad index 0..31
    const int obase = og * 4;         // first of this group's 4 outputs

    // per-thread weights: wv[oo][j] = W_hh[obase+oo][8li+4j .. +3]
    f32x4 wv[4][2];
    #pragma unroll
    for (int oo = 0; oo < 4; ++oo)
        #pragma unroll
        for (int j = 0; j < 2; ++j)
            wv[oo][j] = *(const f32x4*)(W_hh + (obase + oo) * HIDDEN + 8 * li + 4 * j);
    #pragma unroll
    for (int oo = 0; oo < 4; ++oo)
        asm volatile("" : "+v"(wv[oo][0]), "+v"(wv[oo][1]));  // pin in VGPRs

    const float bh = b_hh[obase + (li & 3)];     // used by writer lanes li<4

    // xp register relay: chunk 0 (2048 f32x4 / 512 threads = 4 each)
    const f32x4* xp_g4 = (const f32x4*)xproj;
    f32x4 stg[4];
    #pragma unroll
    for (int i = 0; i < 4; ++i) stg[i] = xp_g4[i * 512 + tid];

    // zero both h buffers (incl. swizzle pad slots)
    if (tid < 72) ((f32x4*)h_swz)[tid] = (f32x4)0.f;

    const int rd_slot = SWZ(2 * li);             // first h float4 slot to read
    const int wr_dw   = 4 * SWZ(og) + (li & 3);  // h write dword (lanes li<4)

    int cur = 0;
    for (int t = 0; t < SEQ; ++t) {
        const int tc = t & (CHUNK - 1);
        if (tc == 0) {                           // chunk boundary (uniform)
            const int c = t >> 6;
            f32x4* dst = (f32x4*)&xp_lds[c & 1][0];
            #pragma unroll
            for (int i = 0; i < 4; ++i) dst[i * 512 + tid] = stg[i];
            step_barrier();                      // chunk (and h-init) visible
            const int cn = (c + 1 < NCHUNK) ? c + 1 : NCHUNK - 1;
            #pragma unroll
            for (int i = 0; i < 4; ++i)          // in flight for next 64 steps
                stg[i] = xp_g4[(size_t)cn * (CHUNK * HIDDEN / 4) + i * 512 + tid];
        }

        // h slice for this lane: 8 floats via 2 ds_read_b128 (imm-offset pair)
        const f32x4 hv0 = h_swz[cur][rd_slot];
        const f32x4 hv1 = h_swz[cur][rd_slot + 1];

        // per-output packed FMA + horizontal sum (vector ops -> pk_fma-able)
        float p[4];
        #pragma unroll
        for (int oo = 0; oo < 4; ++oo) {
            f32x4 a = hv0 * wv[oo][0] + hv1 * wv[oo][1];
            p[oo] = (a[0] + a[1]) + (a[2] + a[3]);
        }
        // 16-lane DPP reduce: every lane gets all 4 group sums
        #pragma unroll
        for (int oo = 0; oo < 4; ++oo) p[oo] = row16_reduce_add(p[oo]);

        // lane (li&3) selects its output's sum; lanes li<4 are the writers
        float v = p[0];
        v = ((li & 3) == 1) ? p[1] : v;
        v = ((li & 3) == 2) ? p[2] : v;
        v = ((li & 3) == 3) ? p[3] : v;

        const float xp = xp_lds[(t >> 6) & 1][tc * HIDDEN + obase + (li & 3)];
        float z = v + xp + bh;
        z = fminf(fmaxf(z, -15.f), 15.f);
        float e2 = __expf(2.f * z);              // tanh = (e^2z-1)/(e^2z+1)
        float hn = (e2 - 1.f) * __builtin_amdgcn_rcpf(e2 + 1.f);
        if (li < 4) ((float*)&h_swz[cur ^ 1][0])[wr_dw] = hn;

        step_barrier();                          // one LDS barrier per step
        cur ^= 1;
    }

    // logits + log_softmax tail (reads swizzled h layout)
    if (tid < OUT) {
        float a = b_fc[tid];
        const float* hp = (const float*)&h_swz[cur][0];
        const float* wf = W_fc + tid * HIDDEN;
        for (int j = 0; j < HIDDEN; ++j) {
            int s4 = j >> 2;
            a += hp[4 * SWZ(s4) + (j & 3)] * wf[j];
        }
        lg[tid] = a;
    }
    __syncthreads();
    if (tid == 0) {
        float m = fmaxf(lg[0], fmaxf(lg[1], lg[2]));
        float s = expf(lg[0] - m) + expf(lg[1] - m) + expf(lg[2] - m);
        float lse = m + logf(s);
        out[0] = lg[0] - lse;
        out[1] = lg[1] - lse;
        out[2] = lg[2] - lse;
    }
}

// ---------------------------------------------------------------------------
extern "C" void kernel_launch(void* const* d_in, const int* in_sizes, int n_in,
                              void* d_out, int out_size, void* d_ws, size_t ws_size,
                              hipStream_t stream) {
    const int*   X       = (const int*)d_in[0];
    const float* weights = (const float*)d_in[1];
    const float* W_ih    = (const float*)d_in[2];
    const float* b_ih    = (const float*)d_in[3];
    const float* W_hh    = (const float*)d_in[4];
    const float* b_hh    = (const float*)d_in[5];
    const float* W_fc    = (const float*)d_in[6];
    const float* b_fc    = (const float*)d_in[7];
    float* out   = (float*)d_out;
    float* xproj = (float*)d_ws;   // SEQ*HIDDEN*4 = 2 MB of scratch

    xproj_kernel<<<SEQ / SPB, 128, 0, stream>>>(X, weights, W_ih, b_ih, xproj);
    rnn_scan_kernel<<<1, 512, 0, stream>>>(xproj, W_hh, b_hh, W_fc, b_fc, out);
}

// Round 11
// 2157.407 us; speedup vs baseline: 1.0700x; 1.0700x over previous
//
#include <hip/hip_runtime.h>
#include <hip/hip_bf16.h>

#define VOCAB   400000
#define EMB     300
#define HIDDEN  128
#define OUT     3
#define SEQ     4096
#define SPB     8     // sequences per block in the xproj kernel
#define PROBE_T 512   // iterations per probe kernel (1/8 of SEQ)

// ---------------------------------------------------------------------------
// Kernel A: xproj[s][i] = b_ih[i] + dot(weights[X[s]], W_ih[i])
// (R4-verified, unchanged)
// ---------------------------------------------------------------------------
__global__ __launch_bounds__(128) void xproj_kernel(
    const int* __restrict__ X, const float* __restrict__ weights,
    const float* __restrict__ W_ih, const float* __restrict__ b_ih,
    float* __restrict__ xproj)
{
    __shared__ float emb[SPB][EMB];
    __shared__ int xs[SPB];
    const int tid = threadIdx.x;
    const int s0 = blockIdx.x * SPB;

    if (tid < SPB) xs[tid] = X[s0 + tid];
    __syncthreads();

    {
        const float4* w4 = (const float4*)weights;
        float4* e4 = (float4*)&emb[0][0];
        for (int i = tid; i < SPB * (EMB / 4); i += 128) {
            int s = i / (EMB / 4);
            int r = i - s * (EMB / 4);
            e4[i] = w4[(size_t)xs[s] * (EMB / 4) + r];
        }
    }
    __syncthreads();

    const float4* wrow = (const float4*)(W_ih + tid * EMB);
    float acc[SPB];
    #pragma unroll
    for (int s = 0; s < SPB; ++s) acc[s] = 0.f;

    #pragma unroll 5
    for (int r = 0; r < EMB / 4; ++r) {
        float4 w = wrow[r];
        #pragma unroll
        for (int s = 0; s < SPB; ++s) {
            float4 e = *(const float4*)&emb[s][4 * r];   // uniform broadcast
            acc[s] += w.x * e.x;
            acc[s] += w.y * e.y;
            acc[s] += w.z * e.z;
            acc[s] += w.w * e.w;
        }
    }

    const float b = b_ih[tid];
    #pragma unroll
    for (int s = 0; s < SPB; ++s)
        xproj[(size_t)(s0 + s) * HIDDEN + tid] = acc[s] + b;
}

// ---------------------------------------------------------------------------
// Quad butterfly sum via DPP quad_perm (full-rate VALU, no LDS round-trip).
// ---------------------------------------------------------------------------
__device__ __forceinline__ float quad_reduce_add(float x) {
    int t = __builtin_amdgcn_update_dpp(0, __float_as_int(x), 0xB1, 0xF, 0xF, true);
    x += __int_as_float(t);
    t = __builtin_amdgcn_update_dpp(0, __float_as_int(x), 0x4E, 0xF, 0xF, true);
    x += __int_as_float(t);
    return x;
}

// ---------------------------------------------------------------------------
// PROBES — decompose the per-step cost. Each runs PROBE_T steps of a strict
// subset of the scan-step structure; per-dispatch dur_us rows in rocprof give
// the breakdown. They write only into d_ws[0..2], which xproj_kernel
// overwrites afterwards (probes are launched FIRST).
// ---------------------------------------------------------------------------

// P1: bare 8-wave barrier loop -> barrier + wave-skew cost per step.
__global__ __launch_bounds__(512) void probe_barrier(float* sink) {
    #pragma unroll 1
    for (int t = 0; t < PROBE_T; ++t) __builtin_amdgcn_s_barrier();
    if (threadIdx.x == 0) sink[0] = 1.f;
}

// P2: + R4-pattern LDS traffic (8 ds_read_b128 + exec-masked write + sync).
__global__ __launch_bounds__(512) void probe_ds(float* sink) {
    __shared__ float h_lds[2][HIDDEN];
    const int tid = threadIdx.x;
    const int o   = tid >> 2;
    const int q   = tid & 3;
    if (tid < HIDDEN) { h_lds[0][tid] = 0.f; h_lds[1][tid] = 0.f; }
    __syncthreads();
    int cur = 0;
    #pragma unroll 1
    for (int t = 0; t < PROBE_T; ++t) {
        const float4* hb = (const float4*)&h_lds[cur][0] + q;
        float s0 = 0.f;
        #pragma unroll
        for (int rr = 0; rr < 8; ++rr) {
            float4 hv = hb[4 * rr];          // same ds_read_b128 pattern as R4
            asm volatile("" :: "v"(hv.x), "v"(hv.y), "v"(hv.z), "v"(hv.w));
            s0 += hv.x;
        }
        if (q == 0) h_lds[cur ^ 1][o] = s0;  // keep the write+lgkm dependency
        __syncthreads();
        cur ^= 1;
    }
    if (tid == 0) sink[1] = h_lds[cur][0];
}

// P3: + FMAs, DPP reduce, tanh (full R4 step body minus the global xp load).
__global__ __launch_bounds__(512) void probe_dsfma(
    const float* __restrict__ W_hh, const float* __restrict__ b_hh, float* sink)
{
    __shared__ float h_lds[2][HIDDEN];
    const int tid = threadIdx.x;
    const int o   = tid >> 2;
    const int q   = tid & 3;
    float4 w[8];
    {
        const float4* wr = (const float4*)(W_hh + o * HIDDEN);
        #pragma unroll
        for (int rr = 0; rr < 8; ++rr) w[rr] = wr[4 * rr + q];
    }
    const float bh = b_hh[o];
    if (tid < HIDDEN) { h_lds[0][tid] = 0.f; h_lds[1][tid] = 0.f; }
    __syncthreads();
    int cur = 0;
    #pragma unroll 1
    for (int t = 0; t < PROBE_T; ++t) {
        const float4* hb = (const float4*)&h_lds[cur][0] + q;
        float a0 = 0.f, a1 = 0.f, a2 = 0.f, a3 = 0.f;
        #pragma unroll
        for (int rr = 0; rr < 8; ++rr) {
            float4 hv = hb[4 * rr];
            a0 += hv.x * w[rr].x;
            a1 += hv.y * w[rr].y;
            a2 += hv.z * w[rr].z;
            a3 += hv.w * w[rr].w;
        }
        float acc = (a0 + a1) + (a2 + a3);
        acc = quad_reduce_add(acc);
        float z = acc + bh;                  // xp omitted: that's main - P3
        z = fminf(fmaxf(z, -15.f), 15.f);
        float e = __expf(2.f * z);
        float hn = (e - 1.f) * __builtin_amdgcn_rcpf(e + 1.f);
        if (q == 0) h_lds[cur ^ 1][o] = hn;
        __syncthreads();
        cur ^= 1;
    }
    if (tid == 0) sink[2] = h_lds[cur][0];
}

// ---------------------------------------------------------------------------
// Kernel B: sequential Elman scan + fc + log_softmax — EXACT R4 structure
// (best measured: 1299 us, 0 bank conflicts). Interleaved quarter partition,
// DPP quad reduce, xp 2-step global prefetch, one __syncthreads per step.
// ---------------------------------------------------------------------------
__global__ __launch_bounds__(512) void rnn_scan_kernel(
    const float* __restrict__ xproj, const float* __restrict__ W_hh,
    const float* __restrict__ b_hh, const float* __restrict__ W_fc,
    const float* __restrict__ b_fc, float* __restrict__ out)
{
    __shared__ float h_lds[2][HIDDEN];
    __shared__ float lg[OUT];

    const int tid = threadIdx.x;
    const int o   = tid >> 2;      // output element 0..127
    const int q   = tid & 3;       // interleave phase

    float4 w[8];
    {
        const float4* wr = (const float4*)(W_hh + o * HIDDEN);
        #pragma unroll
        for (int rr = 0; rr < 8; ++rr) w[rr] = wr[4 * rr + q];
    }
    const float bh = b_hh[o];

    if (tid < HIDDEN) h_lds[0][tid] = 0.f;   // h0 = 0
    float xp0 = xproj[o];                     // xp for t
    float xp1 = xproj[HIDDEN + o];            // xp for t+1
    __syncthreads();

    int cur = 0;
    for (int t = 0; t < SEQ; ++t) {
        const int tn = (t + 2 < SEQ) ? t + 2 : SEQ - 1;
        float xp2 = xproj[(size_t)tn * HIDDEN + o];

        const float4* hb = (const float4*)&h_lds[cur][0] + q;
        float a0 = 0.f, a1 = 0.f, a2 = 0.f, a3 = 0.f;
        #pragma unroll
        for (int rr = 0; rr < 8; ++rr) {
            float4 hv = hb[4 * rr];          // ds_read_b128, conflict-free
            a0 += hv.x * w[rr].x;
            a1 += hv.y * w[rr].y;
            a2 += hv.z * w[rr].z;
            a3 += hv.w * w[rr].w;
        }
        float acc = (a0 + a1) + (a2 + a3);
        acc = quad_reduce_add(acc);          // all 4 quad lanes get the sum

        float z = acc + xp0 + bh;
        z = fminf(fmaxf(z, -15.f), 15.f);
        float e = __expf(2.f * z);           // tanh(z) = (e^2z-1)/(e^2z+1)
        float hn = (e - 1.f) * __builtin_amdgcn_rcpf(e + 1.f);
        if (q == 0) h_lds[cur ^ 1][o] = hn;  // exec-masked 4B write

        __syncthreads();                     // single barrier per step
        cur ^= 1;
        xp0 = xp1;
        xp1 = xp2;
    }

    if (tid < OUT) {
        float a = b_fc[tid];
        const float* wf = W_fc + tid * HIDDEN;
        #pragma unroll 4
        for (int j = 0; j < HIDDEN; ++j) a += h_lds[cur][j] * wf[j];
        lg[tid] = a;
    }
    __syncthreads();
    if (tid == 0) {
        float m = fmaxf(lg[0], fmaxf(lg[1], lg[2]));
        float s = expf(lg[0] - m) + expf(lg[1] - m) + expf(lg[2] - m);
        float lse = m + logf(s);
        out[0] = lg[0] - lse;
        out[1] = lg[1] - lse;
        out[2] = lg[2] - lse;
    }
}

// ---------------------------------------------------------------------------
extern "C" void kernel_launch(void* const* d_in, const int* in_sizes, int n_in,
                              void* d_out, int out_size, void* d_ws, size_t ws_size,
                              hipStream_t stream) {
    const int*   X       = (const int*)d_in[0];
    const float* weights = (const float*)d_in[1];
    const float* W_ih    = (const float*)d_in[2];
    const float* b_ih    = (const float*)d_in[3];
    const float* W_hh    = (const float*)d_in[4];
    const float* b_hh    = (const float*)d_in[5];
    const float* W_fc    = (const float*)d_in[6];
    const float* b_fc    = (const float*)d_in[7];
    float* out   = (float*)d_out;
    float* xproj = (float*)d_ws;   // SEQ*HIDDEN*4 = 2 MB of scratch

    // --- measurement probes (write d_ws[0..2]; xproj overwrites after) ---
    probe_barrier<<<1, 512, 0, stream>>>((float*)d_ws);
    probe_ds<<<1, 512, 0, stream>>>((float*)d_ws);
    probe_dsfma<<<1, 512, 0, stream>>>(W_hh, b_hh, (float*)d_ws);

    // --- real computation ---
    xproj_kernel<<<SEQ / SPB, 128, 0, stream>>>(X, weights, W_ih, b_ih, xproj);
    rnn_scan_kernel<<<1, 512, 0, stream>>>(xproj, W_hh, b_hh, W_fc, b_fc, out);
}